// Round 1
// baseline (32976.129 us; speedup 1.0000x reference)
//
#include <hip/hip_runtime.h>

#define TT 4096
#define BB 64
#define HH 128
#define H1B 136           // h1 base offset (dwords) inside hcat; 136*4 bytes, 16B aligned
#define OUT_HID 262144    // B*T

__device__ __forceinline__ float sigm(float x) {
    return __builtin_amdgcn_rcpf(1.0f + __expf(-x));
}
__device__ __forceinline__ float tanhfast(float x) {
    // tanh(x) = 1 - 2/(exp(2x)+1); saturates correctly at +-inf
    return 1.0f - 2.0f * __builtin_amdgcn_rcpf(1.0f + __expf(2.0f * x));
}

#define FMA4(acc, wv, hv)                                            \
    acc = fmaf((wv).x, (hv).x, acc); acc = fmaf((wv).y, (hv).y, acc); \
    acc = fmaf((wv).z, (hv).z, acc); acc = fmaf((wv).w, (hv).w, acc);

__global__ __launch_bounds__(1024, 4) void gru2_fused(
    const float* __restrict__ data,   // [B, T, 1]
    const float* __restrict__ hidden, // [2, B, H]
    const float* __restrict__ w_ih0,  // [384, 1]
    const float* __restrict__ w_hh0,  // [384, 128]
    const float* __restrict__ b_ih0,  // [384]
    const float* __restrict__ b_hh0,  // [384]
    const float* __restrict__ w_ih1,  // [384, 128]
    const float* __restrict__ w_hh1,  // [384, 128]
    const float* __restrict__ b_ih1,  // [384]
    const float* __restrict__ b_hh1,  // [384]
    const float* __restrict__ fc_w,   // [1, 128]
    const float* __restrict__ fc_b,   // [1]
    float* __restrict__ out)          // [B*T] then [2,B,H]
{
    const int b   = blockIdx.x;
    const int tid = threadIdx.x;
    const bool isL0 = (tid < 512);
    const int lt = isL0 ? tid : (tid - 512);
    const int u  = lt >> 2;   // hidden unit this 4-lane group owns
    const int c  = lt & 3;    // k-chunk index within the group

    __shared__ __align__(16) float hcat[272]; // h0: [0,128), h1: [136,264)

    // ---- per-thread weight registers -------------------------------------
    // L0 thread: rows u, u+128, u+256 of w_hh0, cols [32c, 32c+32)   (96 f)
    // L1 thread: rows u, u+128, u+256 of (c<2 ? w_ih1 : w_hh1),
    //            cols [64*(c&1), +64)                                 (192 f)
    float4 w[3][16];
    if (isL0) {
#pragma unroll
        for (int j = 0; j < 3; ++j) {
            const float4* src = (const float4*)(w_hh0 + (u + 128*j)*128 + 32*c);
#pragma unroll
            for (int i = 0; i < 8; ++i) w[j][i] = src[i];
        }
    } else {
        const float* wm = (c < 2) ? w_ih1 : w_hh1;
        const int colbase = (c & 1) * 64;
#pragma unroll
        for (int j = 0; j < 3; ++j) {
            const float4* src = (const float4*)(wm + (u + 128*j)*128 + colbase);
#pragma unroll
            for (int i = 0; i < 16; ++i) w[j][i] = src[i];
        }
    }

    float br, bz, bin, bhn, wir = 0.f, wiz = 0.f, win = 0.f;
    if (isL0) {
        br  = b_ih0[u]       + b_hh0[u];
        bz  = b_ih0[u + 128] + b_hh0[u + 128];
        bin = b_ih0[u + 256];
        bhn = b_hh0[u + 256];
        wir = w_ih0[u]; wiz = w_ih0[u + 128]; win = w_ih0[u + 256];
    } else {
        br  = b_ih1[u]       + b_hh1[u];
        bz  = b_ih1[u + 128] + b_hh1[u + 128];
        bin = b_ih1[u + 256];
        bhn = b_hh1[u + 256];
    }

    // fc weights for the fc wave (wave 0)
    float fw0 = 0.f, fw1 = 0.f, fb = 0.f;
    if (tid < 64) { fw0 = fc_w[tid]; fw1 = fc_w[tid + 64]; fb = fc_b[0]; }

    // initial hidden state (register copy per 4-lane group + LDS copy)
    float hold = hidden[(isL0 ? 0 : 8192) + b*128 + u];
    if (tid < 128)                 hcat[tid]             = hidden[b*128 + tid];
    if (tid >= 512 && tid < 640)   hcat[H1B + tid - 512] = hidden[8192 + b*128 + (tid - 512)];

    // per-thread LDS read base for its k-chunk
    const float4* hb = isL0
        ? (const float4*)&hcat[32*c]
        : (const float4*)&hcat[(c < 2) ? 64*c : H1B + 64*(c - 2)];

    __syncthreads();

    float fc_pend = 0.f;

    // iter t: L0 computes step t (t<TT); L1 computes step t-1; fc emits step t-2
    for (int t = 0; t < TT + 2; ++t) {
        // store previous fc result early so the pre-barrier vmcnt drain is hidden
        if (tid == 0 && t >= 3) out[b*TT + (t - 3)] = fc_pend;

        const bool l0act = isL0 && (t < TT);
        const bool l1act = (!isL0) && (t >= 1) && (t <= TT);

        // fc partial (wave 0): reads h1(t-2) currently in hcat
        float fcv = 0.f;
        if (tid < 64 && t >= 2) {
            fcv = fmaxf(hcat[H1B + tid], 0.f) * fw0
                + fmaxf(hcat[H1B + 64 + tid], 0.f) * fw1;
        }

        float xv = 0.f;
        float a0 = 0.f, a1 = 0.f, a2 = 0.f;
        if (isL0) {
            if (t < TT) {
                xv = data[b*TT + t];
                float4 hv[8];
#pragma unroll
                for (int i = 0; i < 8; ++i) hv[i] = hb[i];
#pragma unroll
                for (int i = 0; i < 8; ++i) {
                    FMA4(a0, w[0][i], hv[i]);
                    FMA4(a1, w[1][i], hv[i]);
                    FMA4(a2, w[2][i], hv[i]);
                }
            }
        } else {
            if (l1act) {
                float4 hv[16];
#pragma unroll
                for (int i = 0; i < 16; ++i) hv[i] = hb[i];
#pragma unroll
                for (int i = 0; i < 16; ++i) {
                    FMA4(a0, w[0][i], hv[i]);
                    FMA4(a1, w[1][i], hv[i]);
                    FMA4(a2, w[2][i], hv[i]);
                }
            }
        }

        // combine quarter-dots across the 4 owner lanes (adjacent lanes -> DPP)
        float A0 = a0 + __shfl_xor(a0, 1); A0 += __shfl_xor(A0, 2);
        float A1 = a1 + __shfl_xor(a1, 1); A1 += __shfl_xor(A1, 2);
        float s2 = a2 + __shfl_xor(a2, 1);   // pair sums: {c0+c1, c2+c3}
        float o2 = __shfl_xor(s2, 2);        // the other pair's sum

        float hnew = hold;
        if (l0act) {
            float r  = sigm(fmaf(xv, wir, A0 + br));
            float z  = sigm(fmaf(xv, wiz, A1 + bz));
            float hn = (s2 + o2) + bhn;          // full h-side dot
            float xn = fmaf(xv, win, bin);
            float n  = tanhfast(fmaf(r, hn, xn));
            hnew = fmaf(z, hold - n, n);         // n + z*(h - n)
        } else if (l1act) {
            float r  = sigm(A0 + br);
            float z  = sigm(A1 + bz);
            float xn = ((c < 2) ? s2 : o2) + bin; // chunks 0+1 = w_ih1 side
            float hn = ((c < 2) ? o2 : s2) + bhn; // chunks 2+3 = w_hh1 side
            float n  = tanhfast(fmaf(r, hn, xn));
            hnew = fmaf(z, hold - n, n);
        }
        hold = hnew;

        // fc reduction across wave 0
        if (tid < 64 && t >= 2) {
#pragma unroll
            for (int off = 1; off < 64; off <<= 1) fcv += __shfl_xor(fcv, off);
            fc_pend = fcv + fb;
        }

        __syncthreads();                 // all phase-1 LDS reads complete
        if (c == 0) {
            if (l0act)      hcat[u]        = hnew;
            else if (l1act) hcat[H1B + u]  = hnew;
        }
        __syncthreads();                 // new state visible
    }

    // tail: last fc output (t''=TT-1 computed at t=TT+1), final hidden states
    if (tid == 0) out[b*TT + (TT - 1)] = fc_pend;
    if (tid < 128)               out[OUT_HID + b*128 + tid]                = hcat[tid];
    if (tid >= 512 && tid < 640) out[OUT_HID + 8192 + b*128 + (tid - 512)] = hcat[H1B + tid - 512];
}

extern "C" void kernel_launch(void* const* d_in, const int* in_sizes, int n_in,
                              void* d_out, int out_size, void* d_ws, size_t ws_size,
                              hipStream_t stream) {
    (void)in_sizes; (void)n_in; (void)out_size; (void)d_ws; (void)ws_size;
    gru2_fused<<<BB, 1024, 0, stream>>>(
        (const float*)d_in[0],  (const float*)d_in[1],
        (const float*)d_in[2],  (const float*)d_in[3],
        (const float*)d_in[4],  (const float*)d_in[5],
        (const float*)d_in[6],  (const float*)d_in[7],
        (const float*)d_in[8],  (const float*)d_in[9],
        (const float*)d_in[10], (const float*)d_in[11],
        (float*)d_out);
}

// Round 2
// 21547.552 us; speedup vs baseline: 1.5304x; 1.5304x over previous
//
#include <hip/hip_runtime.h>

#define TT 4096
#define BB 64
#define RR 16                 // ring slots per batch (power of 2)
#define OUT_HID (BB*TT)
#define SCOPE __HIP_MEMORY_SCOPE_AGENT

__device__ __forceinline__ float sigm(float x) {
    return __builtin_amdgcn_rcpf(1.0f + __expf(-x));
}
__device__ __forceinline__ float tanhfast(float x) {
    return 1.0f - 2.0f * __builtin_amdgcn_rcpf(1.0f + __expf(2.0f * x));
}

#define FMA4(acc, wv, hv)                                            \
    acc = fmaf((wv).x, (hv).x, acc); acc = fmaf((wv).y, (hv).y, acc); \
    acc = fmaf((wv).z, (hv).z, acc); acc = fmaf((wv).w, (hv).w, acc);

__device__ __forceinline__ void spin_until(unsigned* p, unsigned want) {
    // relaxed poll (agent-scope atomic load bypasses stale L1/L2 line), then
    // one acquire load as the ordering fence (invalidate) once observed.
    while (__hip_atomic_load(p, __ATOMIC_RELAXED, SCOPE) != want)
        __builtin_amdgcn_s_sleep(1);
    (void)__hip_atomic_load(p, __ATOMIC_ACQUIRE, SCOPE);
}

// 3-stage pipeline: role 0 = L0 recurrence, role 1 = L1 x-side GEMV (w_ih1 @ y0),
// role 2 = L1 recurrence + fc.  One block per (role, batch); 192 blocks, all
// co-resident (<=1 block/CU), so cross-block spin is safe.
__global__ __launch_bounds__(512, 2) void gru_pipe(
    const float* __restrict__ data,   const float* __restrict__ hidden,
    const float* __restrict__ w_ih0,  const float* __restrict__ w_hh0,
    const float* __restrict__ b_ih0,  const float* __restrict__ b_hh0,
    const float* __restrict__ w_ih1,  const float* __restrict__ w_hh1,
    const float* __restrict__ b_ih1,  const float* __restrict__ b_hh1,
    const float* __restrict__ fc_w,   const float* __restrict__ fc_b,
    float* __restrict__ out, float* __restrict__ wsf)
{
    const int bid = blockIdx.x;
    const int role = bid >> 6;       // role-major: batch b's 3 blocks land on the same XCD
    const int b   = bid & 63;
    const int tid = threadIdx.x;
    const int u   = tid >> 2;        // unit 0..127
    const int c   = tid & 3;         // k-chunk lane within 4-lane group

    float* y0r = wsf;                              // [BB][RR][128]
    float* xgr = wsf + BB*RR*128;                  // [BB][RR][384]
    unsigned* fl = (unsigned*)(wsf + BB*RR*128 + BB*RR*384);
    unsigned* yflag = fl + 0*BB*RR + b*RR;         // y0 slot published (tag t+1)
    unsigned* ycons = fl + 1*BB*RR + b*RR;         // y0 slot consumed
    unsigned* xflag = fl + 2*BB*RR + b*RR;         // xg1 slot published
    unsigned* xcons = fl + 3*BB*RR + b*RR;         // xg1 slot consumed

    __shared__ __align__(16) float hs[128];

    if (role == 0) {
        // ------------------------- layer-0 recurrence -------------------------
        float4 w[3][8];   // rows u, u+128, u+256 of w_hh0; chunk 4i+c (conflict-free)
#pragma unroll
        for (int j = 0; j < 3; ++j) {
            const float* rp = w_hh0 + (u + 128*j)*128 + 4*c;
#pragma unroll
            for (int i = 0; i < 8; ++i) w[j][i] = *(const float4*)(rp + 16*i);
        }
        const float br  = b_ih0[u]       + b_hh0[u];
        const float bz  = b_ih0[u + 128] + b_hh0[u + 128];
        const float bin = b_ih0[u + 256];
        const float bhn = b_hh0[u + 256];
        const float wir = w_ih0[u], wiz = w_ih0[u + 128], win = w_ih0[u + 256];

        float hold = hidden[b*128 + u];
        if (tid < 128) hs[tid] = hidden[b*128 + tid];
        __syncthreads();

        const float4* hb4 = (const float4*)hs;
        const float*  xp  = data + (size_t)b*TT;

        for (int t = 0; t < TT; ++t) {
            const int s = t & (RR - 1);
            if (tid == 0 && t >= RR) spin_until(&ycons[s], (unsigned)(t - RR + 1));
            const float xv = xp[t];
            float a0 = 0.f, a1 = 0.f, a2 = 0.f;
#pragma unroll
            for (int i = 0; i < 8; ++i) {
                float4 hv = hb4[4*i + c];
                FMA4(a0, w[0][i], hv); FMA4(a1, w[1][i], hv); FMA4(a2, w[2][i], hv);
            }
            float A0 = a0 + __shfl_xor(a0, 1); A0 += __shfl_xor(A0, 2);
            float A1 = a1 + __shfl_xor(a1, 1); A1 += __shfl_xor(A1, 2);
            float A2 = a2 + __shfl_xor(a2, 1); A2 += __shfl_xor(A2, 2);
            const float r = sigm(fmaf(xv, wir, A0 + br));
            const float z = sigm(fmaf(xv, wiz, A1 + bz));
            const float n = tanhfast(fmaf(r, A2 + bhn, fmaf(xv, win, bin)));
            const float hnew = fmaf(z, hold - n, n);
            __syncthreads();                       // readers done + backpressure ok
            if (c == 0) {
                hs[u] = hnew;
                y0r[((size_t)b*RR + s)*128 + u] = hnew;
            }
            __syncthreads();                       // drains vmcnt before release
            if (tid == 0)
                __hip_atomic_store(&yflag[s], (unsigned)(t + 1), __ATOMIC_RELEASE, SCOPE);
            hold = hnew;
        }
        if (tid < 128) out[OUT_HID + b*128 + tid] = hs[tid];

    } else if (role == 1) {
        // ---------------- layer-1 input-side GEMV: xg1(t) = w_ih1 . y0(t) ----------------
        float4 w[3][8];
#pragma unroll
        for (int j = 0; j < 3; ++j) {
            const float* rp = w_ih1 + (u + 128*j)*128 + 4*c;
#pragma unroll
            for (int i = 0; i < 8; ++i) w[j][i] = *(const float4*)(rp + 16*i);
        }
        for (int t = 0; t < TT; ++t) {
            const int s = t & (RR - 1);
            if (tid == 0) {
                spin_until(&yflag[s], (unsigned)(t + 1));
                if (t >= RR) spin_until(&xcons[s], (unsigned)(t - RR + 1));
            }
            __syncthreads();
            const float4* yb = (const float4*)(y0r + ((size_t)b*RR + s)*128);
            float a0 = 0.f, a1 = 0.f, a2 = 0.f;
#pragma unroll
            for (int i = 0; i < 8; ++i) {
                float4 yv = yb[4*i + c];
                FMA4(a0, w[0][i], yv); FMA4(a1, w[1][i], yv); FMA4(a2, w[2][i], yv);
            }
            float A0 = a0 + __shfl_xor(a0, 1); A0 += __shfl_xor(A0, 2);
            float A1 = a1 + __shfl_xor(a1, 1); A1 += __shfl_xor(A1, 2);
            float A2 = a2 + __shfl_xor(a2, 1); A2 += __shfl_xor(A2, 2);
            if (c == 0) {
                float* xg = xgr + ((size_t)b*RR + s)*384;
                xg[u] = A0; xg[u + 128] = A1; xg[u + 256] = A2;
            }
            __syncthreads();
            if (tid == 0) {
                __hip_atomic_store(&xflag[s], (unsigned)(t + 1), __ATOMIC_RELEASE, SCOPE);
                __hip_atomic_store(&ycons[s], (unsigned)(t + 1), __ATOMIC_RELEASE, SCOPE);
            }
        }

    } else {
        // ------------------- layer-1 recurrence + fc head -------------------
        float4 w[3][8];
#pragma unroll
        for (int j = 0; j < 3; ++j) {
            const float* rp = w_hh1 + (u + 128*j)*128 + 4*c;
#pragma unroll
            for (int i = 0; i < 8; ++i) w[j][i] = *(const float4*)(rp + 16*i);
        }
        const float br  = b_ih1[u]       + b_hh1[u];
        const float bz  = b_ih1[u + 128] + b_hh1[u + 128];
        const float bin = b_ih1[u + 256];
        const float bhn = b_hh1[u + 256];
        float fw0 = 0.f, fw1 = 0.f, fb = 0.f;
        if (tid < 64) { fw0 = fc_w[tid]; fw1 = fc_w[tid + 64]; fb = fc_b[0]; }

        float hold = hidden[8192 + b*128 + u];
        if (tid < 128) hs[tid] = hidden[8192 + b*128 + tid];
        __syncthreads();

        const float4* hb4 = (const float4*)hs;
        float* outp = out + (size_t)b*TT;

        for (int t = 0; t < TT; ++t) {
            const int s = t & (RR - 1);
            if (tid == 0) spin_until(&xflag[s], (unsigned)(t + 1));
            __syncthreads();
            const float* xg = xgr + ((size_t)b*RR + s)*384;
            const float xr = xg[u], xz = xg[u + 128], xn = xg[u + 256];
            // fc for step t-1 (reads pre-update hs)
            float fcv = 0.f;
            if (tid < 64 && t >= 1)
                fcv = fmaxf(hs[tid], 0.f)*fw0 + fmaxf(hs[tid + 64], 0.f)*fw1;
            float a0 = 0.f, a1 = 0.f, a2 = 0.f;
#pragma unroll
            for (int i = 0; i < 8; ++i) {
                float4 hv = hb4[4*i + c];
                FMA4(a0, w[0][i], hv); FMA4(a1, w[1][i], hv); FMA4(a2, w[2][i], hv);
            }
            float A0 = a0 + __shfl_xor(a0, 1); A0 += __shfl_xor(A0, 2);
            float A1 = a1 + __shfl_xor(a1, 1); A1 += __shfl_xor(A1, 2);
            float A2 = a2 + __shfl_xor(a2, 1); A2 += __shfl_xor(A2, 2);
            const float r = sigm(xr + A0 + br);
            const float z = sigm(xz + A1 + bz);
            const float n = tanhfast(fmaf(r, A2 + bhn, xn + bin));
            const float hnew = fmaf(z, hold - n, n);
            if (tid < 64 && t >= 1) {
#pragma unroll
                for (int off = 1; off < 64; off <<= 1) fcv += __shfl_xor(fcv, off);
                if (tid == 0) outp[t - 1] = fcv + fb;
            }
            __syncthreads();                       // readers of hs done
            if (c == 0) hs[u] = hnew;
            __syncthreads();
            if (tid == 0)
                __hip_atomic_store(&xcons[s], (unsigned)(t + 1), __ATOMIC_RELEASE, SCOPE);
            hold = hnew;
        }
        // tail: fc for t = TT-1, final hidden state
        float fcv = 0.f;
        if (tid < 64) {
            fcv = fmaxf(hs[tid], 0.f)*fw0 + fmaxf(hs[tid + 64], 0.f)*fw1;
#pragma unroll
            for (int off = 1; off < 64; off <<= 1) fcv += __shfl_xor(fcv, off);
            if (tid == 0) outp[TT - 1] = fcv + fb;
        }
        if (tid < 128) out[OUT_HID + 8192 + b*128 + tid] = hs[tid];
    }
}

extern "C" void kernel_launch(void* const* d_in, const int* in_sizes, int n_in,
                              void* d_out, int out_size, void* d_ws, size_t ws_size,
                              hipStream_t stream) {
    (void)in_sizes; (void)n_in; (void)out_size; (void)ws_size;
    gru_pipe<<<192, 512, 0, stream>>>(
        (const float*)d_in[0],  (const float*)d_in[1],
        (const float*)d_in[2],  (const float*)d_in[3],
        (const float*)d_in[4],  (const float*)d_in[5],
        (const float*)d_in[6],  (const float*)d_in[7],
        (const float*)d_in[8],  (const float*)d_in[9],
        (const float*)d_in[10], (const float*)d_in[11],
        (float*)d_out, (float*)d_ws);
}

// Round 3
// 5097.211 us; speedup vs baseline: 6.4694x; 4.2273x over previous
//
#include <hip/hip_runtime.h>

#define TT 4096
#define BB 64
#define RR 16
#define OUT_HID (BB*TT)

#define SYS_LDU(p)    __hip_atomic_load((p),      __ATOMIC_RELAXED, __HIP_MEMORY_SCOPE_SYSTEM)
#define SYS_STU(p,v)  __hip_atomic_store((p),(v), __ATOMIC_RELAXED, __HIP_MEMORY_SCOPE_SYSTEM)
#define SYS_STF(p,v)  __hip_atomic_store((p),(v), __ATOMIC_RELAXED, __HIP_MEMORY_SCOPE_SYSTEM)

__device__ __forceinline__ float sigm(float x) {
    return __builtin_amdgcn_rcpf(1.0f + __expf(-x));
}
__device__ __forceinline__ float tanhfast(float x) {
    return 1.0f - 2.0f * __builtin_amdgcn_rcpf(1.0f + __expf(2.0f * x));
}

#define FMA4(acc, wv, hv)                                            \
    acc = fmaf((wv).x, (hv).x, acc); acc = fmaf((wv).y, (hv).y, acc); \
    acc = fmaf((wv).z, (hv).z, acc); acc = fmaf((wv).w, (hv).w, acc);

#define X8(M) M(0) M(1) M(2) M(3) M(4) M(5) M(6) M(7)

// 24 individually-named float4 weight registers (cannot be scratch-demoted)
#define DECLW(i) float4 wA##i, wB##i, wC##i;
#define LDW(i)   wA##i = *(const float4*)(rpA + 16*(i)); \
                 wB##i = *(const float4*)(rpB + 16*(i)); \
                 wC##i = *(const float4*)(rpC + 16*(i));
#define DECLY(i) float4 y##i;
#define GEMV_LDS(i) { float4 hv_ = hb4[4*(i) + c]; \
    FMA4(a0, wA##i, hv_); FMA4(a1, wB##i, hv_); FMA4(a2, wC##i, hv_); }
#define GEMV_Y(i) { FMA4(a0, wA##i, y##i); FMA4(a1, wB##i, y##i); FMA4(a2, wC##i, y##i); }

#define RED3() \
    float A0 = a0 + __shfl_xor(a0, 1); A0 += __shfl_xor(A0, 2); \
    float A1 = a1 + __shfl_xor(a1, 1); A1 += __shfl_xor(A1, 2); \
    float A2 = a2 + __shfl_xor(a2, 1); A2 += __shfl_xor(A2, 2);

// Roles: 0 = L0 recurrence, 1 = L1 x-GEMV (even t), 2 = L1 x-GEMV (odd t),
// 3 = L1 recurrence + fc.  256 blocks = 256 CUs, all co-resident.
// Ring handoff: system-scope relaxed (sc0 sc1) data+flags meeting at L3;
// producer orders data-before-flag via __syncthreads()'s vmcnt(0) drain.
__global__ __launch_bounds__(512, 2) void gru_pipe(
    const float* __restrict__ data,   const float* __restrict__ hidden,
    const float* __restrict__ w_ih0,  const float* __restrict__ w_hh0,
    const float* __restrict__ b_ih0,  const float* __restrict__ b_hh0,
    const float* __restrict__ w_ih1,  const float* __restrict__ w_hh1,
    const float* __restrict__ b_ih1,  const float* __restrict__ b_hh1,
    const float* __restrict__ fc_w,   const float* __restrict__ fc_b,
    float* __restrict__ out, float* __restrict__ wsf)
{
    const int bid  = blockIdx.x;
    const int role = bid >> 6;      // batch b's 4 blocks all land on XCD b%8
    const int b    = bid & 63;
    const int tid  = threadIdx.x;
    const int u    = tid >> 2;      // hidden unit 0..127
    const int c    = tid & 3;       // k-chunk lane in the 4-lane group

    float* y0r = wsf;                               // [BB][RR][128]
    float* xgr = wsf + BB*RR*128;                   // [BB][RR][384]
    unsigned* fl   = (unsigned*)(wsf + BB*RR*128 + BB*RR*384);
    unsigned* yflag = fl + 0*BB*RR + b*RR;
    unsigned* ycons = fl + 1*BB*RR + b*RR;
    unsigned* xflag = fl + 2*BB*RR + b*RR;
    unsigned* xcons = fl + 3*BB*RR + b*RR;

    __shared__ __align__(16) float hs[128];
    __shared__ float xs[TT];                        // role-0 input stage (16 KB)

    if (role == 0) {
        // ----------------------------- L0 recurrence -----------------------------
        X8(DECLW)
        { const float* rpA = w_hh0 + u*128 + 4*c;
          const float* rpB = rpA + 16384; const float* rpC = rpA + 32768;
          X8(LDW) }
        const float br  = b_ih0[u]       + b_hh0[u];
        const float bz  = b_ih0[u + 128] + b_hh0[u + 128];
        const float bin = b_ih0[u + 256];
        const float bhn = b_hh0[u + 256];
        const float wir = w_ih0[u], wiz = w_ih0[u + 128], win = w_ih0[u + 256];

        float hold = hidden[b*128 + u];
        if (tid < 128) hs[tid] = hidden[b*128 + tid];
        { const float* xp = data + (size_t)b*TT;
          for (int i = tid; i < TT; i += 512) xs[i] = xp[i]; }
        __syncthreads();

        const float4* hb4 = (const float4*)hs;
        float* yr = y0r + (size_t)b*RR*128;
        unsigned g = 0;

        for (int t = 0; t < TT; ++t) {
            const int s = t & (RR - 1);
            if (t >= RR) {
                while (g != (unsigned)(t - RR + 1)) {
                    __builtin_amdgcn_s_sleep(1); g = SYS_LDU(&ycons[s]);
                }
            }
            const float xv = xs[t];
            float a0 = 0.f, a1 = 0.f, a2 = 0.f;
            X8(GEMV_LDS)
            RED3()
            const float r = sigm(fmaf(xv, wir, A0 + br));
            const float z = sigm(fmaf(xv, wiz, A1 + bz));
            const float n = tanhfast(fmaf(r, A2 + bhn, fmaf(xv, win, bin)));
            const float hnew = fmaf(z, hold - n, n);
            __syncthreads();                         // readers of hs done
            if (c == 0) { hs[u] = hnew; SYS_STF(&yr[s*128 + u], hnew); }
            __syncthreads();                         // drains vmcnt: y0 at L3
            if (tid == 0) SYS_STU(&yflag[s], (unsigned)(t + 1));
            if (t + 1 >= RR) g = SYS_LDU(&ycons[(t + 1) & (RR - 1)]);  // prefetch
            hold = hnew;
        }
        if (tid < 128) out[OUT_HID + b*128 + tid] = hs[tid];

    } else if (role <= 2) {
        // --------------- L1 x-side GEMV, split by timestep parity ---------------
        X8(DECLW)
        { const float* rpA = w_ih1 + u*128 + 4*c;
          const float* rpB = rpA + 16384; const float* rpC = rpA + 32768;
          X8(LDW) }
        X8(DECLY)
        const int par = role - 1;
        float* xg = xgr + (size_t)b*RR*384;
        const float* yrd = y0r + (size_t)b*RR*128;

        for (int t = par; t < TT; t += 2) {
            const int s = t & (RR - 1);
            while (SYS_LDU(&yflag[s]) != (unsigned)(t + 1)) __builtin_amdgcn_s_sleep(1);
            if (t >= RR)
                while (SYS_LDU(&xcons[s]) != (unsigned)(t - RR + 1)) __builtin_amdgcn_s_sleep(1);
            const float4* yb = (const float4*)(yrd + s*128 + 4*c);
            asm volatile(
                "global_load_dwordx4 %0, %8, off sc0 sc1\n\t"
                "global_load_dwordx4 %1, %8, off offset:64 sc0 sc1\n\t"
                "global_load_dwordx4 %2, %8, off offset:128 sc0 sc1\n\t"
                "global_load_dwordx4 %3, %8, off offset:192 sc0 sc1\n\t"
                "global_load_dwordx4 %4, %8, off offset:256 sc0 sc1\n\t"
                "global_load_dwordx4 %5, %8, off offset:320 sc0 sc1\n\t"
                "global_load_dwordx4 %6, %8, off offset:384 sc0 sc1\n\t"
                "global_load_dwordx4 %7, %8, off offset:448 sc0 sc1\n\t"
                "s_waitcnt vmcnt(0)"
                : "=&v"(y0), "=&v"(y1), "=&v"(y2), "=&v"(y3),
                  "=&v"(y4), "=&v"(y5), "=&v"(y6), "=&v"(y7)
                : "v"(yb) : "memory");
            float a0 = 0.f, a1 = 0.f, a2 = 0.f;
            X8(GEMV_Y)
            RED3()
            if (c == 0) {
                SYS_STF(&xg[s*384 + u],       A0);
                SYS_STF(&xg[s*384 + 128 + u], A1);
                SYS_STF(&xg[s*384 + 256 + u], A2);
            }
            __syncthreads();                         // drains vmcnt: xg at L3
            if (tid == 0) {
                SYS_STU(&xflag[s], (unsigned)(t + 1));
                SYS_STU(&ycons[s], (unsigned)(t + 1));
            }
        }

    } else {
        // ------------------------ L1 recurrence + fc head ------------------------
        X8(DECLW)
        { const float* rpA = w_hh1 + u*128 + 4*c;
          const float* rpB = rpA + 16384; const float* rpC = rpA + 32768;
          X8(LDW) }
        const float br  = b_ih1[u]       + b_hh1[u];
        const float bz  = b_ih1[u + 128] + b_hh1[u + 128];
        const float bin = b_ih1[u + 256];
        const float bhn = b_hh1[u + 256];
        float fw0 = 0.f, fw1 = 0.f, fb = 0.f;
        if (tid < 64) { fw0 = fc_w[tid]; fw1 = fc_w[tid + 64]; fb = fc_b[0]; }

        float hold = hidden[8192 + b*128 + u];
        if (tid < 128) hs[tid] = hidden[8192 + b*128 + tid];
        __syncthreads();

        const float4* hb4 = (const float4*)hs;
        const float* xgd = xgr + (size_t)b*RR*384;
        float* outp = out + (size_t)b*TT;
        unsigned f = SYS_LDU(&xflag[0]);

        for (int t = 0; t < TT; ++t) {
            const int s = t & (RR - 1);
            while (f != (unsigned)(t + 1)) { __builtin_amdgcn_s_sleep(1); f = SYS_LDU(&xflag[s]); }
            const float* xgp = xgd + s*384 + u;
            float xr, xz, xn;
            asm volatile(                            // issue-early, wait-late
                "global_load_dword %0, %3, off sc0 sc1\n\t"
                "global_load_dword %1, %3, off offset:512 sc0 sc1\n\t"
                "global_load_dword %2, %3, off offset:1024 sc0 sc1"
                : "=&v"(xr), "=&v"(xz), "=&v"(xn) : "v"(xgp) : "memory");
            if (t + 1 < TT) f = SYS_LDU(&xflag[(t + 1) & (RR - 1)]);   // prefetch poll
            float fcv = 0.f;
            if (tid < 64 && t >= 1)
                fcv = fmaxf(hs[tid], 0.f)*fw0 + fmaxf(hs[tid + 64], 0.f)*fw1;
            float a0 = 0.f, a1 = 0.f, a2 = 0.f;
            X8(GEMV_LDS)                             // xg latency hides under this
            RED3()
            asm volatile("s_waitcnt vmcnt(0)" : "+v"(xr), "+v"(xz), "+v"(xn));
            const float r = sigm(xr + A0 + br);
            const float z = sigm(xz + A1 + bz);
            const float n = tanhfast(fmaf(r, A2 + bhn, xn + bin));
            const float hnew = fmaf(z, hold - n, n);
            if (tid < 64 && t >= 1) {
#pragma unroll
                for (int off = 1; off < 64; off <<= 1) fcv += __shfl_xor(fcv, off);
                if (tid == 0) outp[t - 1] = fcv + fb;
            }
            __syncthreads();
            if (c == 0) hs[u] = hnew;
            __syncthreads();
            if (tid == 0) SYS_STU(&xcons[s], (unsigned)(t + 1));
            hold = hnew;
        }
        float fcv = 0.f;
        if (tid < 64) {
            fcv = fmaxf(hs[tid], 0.f)*fw0 + fmaxf(hs[tid + 64], 0.f)*fw1;
#pragma unroll
            for (int off = 1; off < 64; off <<= 1) fcv += __shfl_xor(fcv, off);
            if (tid == 0) outp[TT - 1] = fcv + fb;
        }
        if (tid < 128) out[OUT_HID + 8192 + b*128 + tid] = hs[tid];
    }
}

extern "C" void kernel_launch(void* const* d_in, const int* in_sizes, int n_in,
                              void* d_out, int out_size, void* d_ws, size_t ws_size,
                              hipStream_t stream) {
    (void)in_sizes; (void)n_in; (void)out_size; (void)ws_size;
    gru_pipe<<<256, 512, 0, stream>>>(
        (const float*)d_in[0],  (const float*)d_in[1],
        (const float*)d_in[2],  (const float*)d_in[3],
        (const float*)d_in[4],  (const float*)d_in[5],
        (const float*)d_in[6],  (const float*)d_in[7],
        (const float*)d_in[8],  (const float*)d_in[9],
        (const float*)d_in[10], (const float*)d_in[11],
        (float*)d_out, (float*)d_ws);
}